// Round 2
// baseline (228.379 us; speedup 1.0000x reference)
//
#include <hip/hip_runtime.h>

#define B_DIM 8
#define T_DIM 2048
#define C_DIM 1024
#define H_DIM 128

typedef __attribute__((ext_vector_type(8))) short bf16x8;
typedef __attribute__((ext_vector_type(4))) float f32x4;

__device__ __forceinline__ short f2bf(float f) {
  union { float f; unsigned u; } v; v.f = f;
  unsigned u = v.u;
  unsigned r = (u + 0x7FFFu + ((u >> 16) & 1u)) >> 16;
  return (short)r;
}

__device__ __forceinline__ void gload_lds16(const short* g, short* l) {
  __builtin_amdgcn_global_load_lds(
      (const __attribute__((address_space(1))) void*)g,
      (__attribute__((address_space(3))) void*)l, 16, 0, 0);
}

// ---------------------------------------------------------------------------
// Kernel 1: prep.  (a) x fp32 -> bf16 (xb, [B*T][C]).  (b) weights fp32 ->
// bf16 transposed: Wt[3][H=128][C=1024], 16B coalesced writes.
// ---------------------------------------------------------------------------
#define NXE ((B_DIM * T_DIM * C_DIM) / 8)   // 2097152 x-items (8 elems each)
#define NWE ((3 * C_DIM * H_DIM) / 8)       // 49152 w-items

__global__ __launch_bounds__(256) void prep_kernel(
    const float* __restrict__ x, const float* __restrict__ Wk,
    const float* __restrict__ Wq, const float* __restrict__ Wv,
    short* __restrict__ xb, short* __restrict__ Wt) {
  int gid = blockIdx.x * 256 + threadIdx.x;
  if (gid < NXE) {
    const float* src = x + (size_t)gid * 8;
    float4 f0 = ((const float4*)src)[0];
    float4 f1 = ((const float4*)src)[1];
    __attribute__((aligned(16))) short t[8];
    t[0] = f2bf(f0.x); t[1] = f2bf(f0.y); t[2] = f2bf(f0.z); t[3] = f2bf(f0.w);
    t[4] = f2bf(f1.x); t[5] = f2bf(f1.y); t[6] = f2bf(f1.z); t[7] = f2bf(f1.w);
    ((int4*)xb)[gid] = *(const int4*)t;
  } else {
    int j = gid - NXE;
    if (j >= NWE) return;
    int w = j >> 14;             // /16384 items per weight
    int r = j & 16383;
    int h = r >> 7;              // C/8 = 128 items per h
    int c0 = (r & 127) * 8;
    const float* W = (w == 0) ? Wk : ((w == 1) ? Wq : Wv);
    __attribute__((aligned(16))) short t[8];
#pragma unroll
    for (int i = 0; i < 8; i++) t[i] = f2bf(W[(size_t)(c0 + i) * H_DIM + h]);
    *(int4*)(Wt + (size_t)w * (C_DIM * H_DIM) + h * C_DIM + c0) = *(const int4*)t;
  }
}

// ---------------------------------------------------------------------------
// Kernel 2: projection GEMM.  Tile 64x128, BK=64, 4 waves (2x2, 32x64 each).
// Grid (256,3) = 768 blocks = 3 blocks/CU -> real inter-block overlap hides
// the per-iteration barrier drain (round-1's (128,3)=1.5/CU did not).
// wi = 0 -> K, 1 -> Q (row-major [t][h]), 2 -> V transposed ([h][t]).
// ---------------------------------------------------------------------------
__global__ __launch_bounds__(256) void proj_kernel(
    const short* __restrict__ xb, const short* __restrict__ Wt,
    short* __restrict__ Kb, short* __restrict__ Qb, short* __restrict__ Vt) {
  const int wi = blockIdx.y;
  const int m0 = blockIdx.x * 64;
  __shared__ short As[64 * 64];    // [row][64] linear (gload_lds needs linear)
  __shared__ short Bs[128 * 64];
  const int tid  = threadIdx.x;
  const int lane = tid & 63;
  const int wv   = tid >> 6;
  const int n    = lane & 15;
  const int quad = lane >> 4;
  const int mbase = (wv >> 1) * 32;
  const int nbase = (wv & 1) * 64;
  const short* Wp = Wt + (size_t)wi * (C_DIM * H_DIM);

  const int crow = lane >> 3;        // 0..7 row within 1KB chunk
  const int ccol = (lane & 7) * 8;   // element offset 0..56

  f32x4 acc[2][4];
#pragma unroll
  for (int i = 0; i < 2; i++)
#pragma unroll
    for (int j = 0; j < 4; j++) {
      f32x4 z = {0.f, 0.f, 0.f, 0.f};
      acc[i][j] = z;
    }

  for (int k0 = 0; k0 < C_DIM; k0 += 64) {
    __syncthreads();
    // 24 x 1KB chunks (A: 8, B: 16), 6 per wave, wave-uniform LDS base
#pragma unroll
    for (int h = 0; h < 6; h++) {
      int c = wv * 6 + h;
      if (c < 8) {
        gload_lds16(xb + (size_t)(m0 + c * 8 + crow) * C_DIM + k0 + ccol,
                    &As[c * 512]);
      } else {
        int cb = c - 8;
        gload_lds16(Wp + (size_t)(cb * 8 + crow) * C_DIM + k0 + ccol,
                    &Bs[cb * 512]);
      }
    }
    __syncthreads();   // compiler drains vmcnt here (m97 structure)

#pragma unroll
    for (int kk = 0; kk < 2; kk++) {
      bf16x8 aF[2], bF[4];
#pragma unroll
      for (int mt = 0; mt < 2; mt++)
        aF[mt] = *(const bf16x8*)&As[(mbase + mt * 16 + n) * 64 + kk * 32 + quad * 8];
#pragma unroll
      for (int nt = 0; nt < 4; nt++)
        bF[nt] = *(const bf16x8*)&Bs[(nbase + nt * 16 + n) * 64 + kk * 32 + quad * 8];
#pragma unroll
      for (int mt = 0; mt < 2; mt++)
#pragma unroll
        for (int nt = 0; nt < 4; nt++)
          acc[mt][nt] = __builtin_amdgcn_mfma_f32_16x16x32_bf16(
              aF[mt], bF[nt], acc[mt][nt], 0, 0, 0);
    }
  }

  // epilogue: C/D layout col = lane&15, row = quad*4 + reg
#pragma unroll
  for (int mt = 0; mt < 2; mt++) {
#pragma unroll
    for (int nt = 0; nt < 4; nt++) {
#pragma unroll
      for (int i = 0; i < 4; i++) {
        int row = m0 + mbase + mt * 16 + quad * 4 + i;   // token index
        int col = nbase + nt * 16 + n;                   // h index
        short v = f2bf(acc[mt][nt][i]);
        if (wi == 0) {
          Kb[(size_t)row * H_DIM + col] = v;
        } else if (wi == 1) {
          Qb[(size_t)row * H_DIM + col] = v;
        } else {
          int bb = row >> 11;
          int t = row & (T_DIM - 1);
          Vt[((size_t)bb * H_DIM + col) * T_DIM + t] = v;
        }
      }
    }
  }
}

// ---------------------------------------------------------------------------
// Kernel 3: causal flash attention — NO K/V LDS staging, NO main-loop
// barriers.  Per-batch K+V = 1MB, L2-resident (XCD-pinned via id%8 remap);
// B-fragments are read straight from global (16B/lane, 64B segments).
// Block = 512 thr = 8 waves: (ws = q-strip of 16 rows x 2, g = kv-phase x 4).
// Each wave runs its tile stream independently; 4-way partials merged once
// at the end through LDS.  512 blocks x 8 waves = 4 waves/SIMD.
// ---------------------------------------------------------------------------
__global__ __launch_bounds__(512, 4) void attn_kernel(
    const short* __restrict__ Qb, const short* __restrict__ Kb,
    const short* __restrict__ Vt, float* __restrict__ out) {
  const int id = blockIdx.y * 64 + blockIdx.x;
  const int b  = id & 7;            // batch -> XCD pinning (id%8 = XCD)
  const int q0 = (id >> 3) * 32;
  const int tid  = threadIdx.x;
  const int lane = tid & 63;
  const int wv   = tid >> 6;   // 0..7
  const int g    = wv & 3;     // kv phase
  const int ws   = wv >> 2;    // q strip (16 rows)
  const int n    = lane & 15;
  const int quad = lane >> 4;

  __shared__ short Ps[8][16][72];     // per-wave P strips (18KB)
  __shared__ float Om[2][16][128];    // merge buffer (16KB)
  __shared__ float Ml[2][16][2];

  const int ntiles = ((q0 + 31) >> 6) + 1;
  const float scale = 0.08838834764831845f;  // 1/sqrt(128)
  const int row0 = q0 + ws * 16 + quad * 4;  // + reg i

  // Q A-frags, register-resident
  bf16x8 aQ[4];
  {
    const short* qrow = Qb + (size_t)(b * T_DIM + q0 + ws * 16 + n) * H_DIM;
#pragma unroll
    for (int kc = 0; kc < 4; kc++)
      aQ[kc] = *(const bf16x8*)(qrow + kc * 32 + quad * 8);
  }

  f32x4 accO[8];
#pragma unroll
  for (int i = 0; i < 8; i++) {
    f32x4 z = {0.f, 0.f, 0.f, 0.f};
    accO[i] = z;
  }
  float mrow[4] = {-1e30f, -1e30f, -1e30f, -1e30f};
  float lrow[4] = {0.f, 0.f, 0.f, 0.f};

  const short* Kb0 = Kb + (size_t)b * T_DIM * H_DIM;
  const short* Vb0 = Vt + (size_t)b * H_DIM * T_DIM;

  for (int t = g; t < ntiles; t += 4) {
    const int j0 = t * 64;
    // S = Q K^T (16 x 64), K B-frags direct from global (L1/L2)
    f32x4 accS[4];
#pragma unroll
    for (int nt = 0; nt < 4; nt++) {
      f32x4 z = {0.f, 0.f, 0.f, 0.f};
      accS[nt] = z;
    }
#pragma unroll
    for (int nt = 0; nt < 4; nt++) {
      const short* kr = Kb0 + (size_t)(j0 + nt * 16 + n) * H_DIM;
#pragma unroll
      for (int kc = 0; kc < 4; kc++) {
        bf16x8 bK = *(const bf16x8*)(kr + kc * 32 + quad * 8);
        accS[nt] = __builtin_amdgcn_mfma_f32_16x16x32_bf16(aQ[kc], bK, accS[nt], 0, 0, 0);
      }
    }
    // scale + causal mask (in place) + online softmax
    float mt4[4] = {-1e30f, -1e30f, -1e30f, -1e30f};
#pragma unroll
    for (int nt = 0; nt < 4; nt++) {
      int col = j0 + nt * 16 + n;
#pragma unroll
      for (int i = 0; i < 4; i++) {
        float s = accS[nt][i] * scale;
        s = (col > row0 + i) ? -1e30f : s;
        accS[nt][i] = s;
        mt4[i] = fmaxf(mt4[i], s);
      }
    }
#pragma unroll
    for (int i = 0; i < 4; i++) {
#pragma unroll
      for (int off = 1; off < 16; off <<= 1)
        mt4[i] = fmaxf(mt4[i], __shfl_xor(mt4[i], off, 64));
    }
    float alpha[4], rsum[4];
#pragma unroll
    for (int i = 0; i < 4; i++) {
      float mnew = fmaxf(mrow[i], mt4[i]);
      alpha[i] = __expf(mrow[i] - mnew);
      mrow[i] = mnew;
      rsum[i] = 0.f;
    }
#pragma unroll
    for (int nt = 0; nt < 4; nt++)
#pragma unroll
      for (int i = 0; i < 4; i++) {
        float p = __expf(accS[nt][i] - mrow[i]);
        rsum[i] += p;
        Ps[wv][quad * 4 + i][nt * 16 + n] = f2bf(p);
      }
#pragma unroll
    for (int i = 0; i < 4; i++) {
#pragma unroll
      for (int off = 1; off < 16; off <<= 1)
        rsum[i] += __shfl_xor(rsum[i], off, 64);
      lrow[i] = lrow[i] * alpha[i] + rsum[i];
    }
#pragma unroll
    for (int ht = 0; ht < 8; ht++)
#pragma unroll
      for (int i = 0; i < 4; i++)
        accO[ht][i] *= alpha[i];

    // P strip is written and read by the SAME wave: lgkmcnt wait suffices
    asm volatile("s_waitcnt lgkmcnt(0)" ::: "memory");
    __builtin_amdgcn_sched_barrier(0);

    // O += P V: V^T B-frags direct from global (contiguous 16B in t)
    bf16x8 aP[2];
#pragma unroll
    for (int kc = 0; kc < 2; kc++)
      aP[kc] = *(const bf16x8*)&Ps[wv][n][kc * 32 + quad * 8];
#pragma unroll
    for (int ht = 0; ht < 8; ht++) {
      const short* vr = Vb0 + (size_t)(ht * 16 + n) * T_DIM + j0;
#pragma unroll
      for (int kc = 0; kc < 2; kc++) {
        bf16x8 bV = *(const bf16x8*)(vr + kc * 32 + quad * 8);
        accO[ht] = __builtin_amdgcn_mfma_f32_16x16x32_bf16(aP[kc], bV, accO[ht], 0, 0, 0);
      }
    }
  }

  // ---- merge the 4 kv-phase partials per q-strip (only barriers here) ----
  __syncthreads();
  if (g == 0) {
#pragma unroll
    for (int i = 0; i < 4; i++) {
      int r = quad * 4 + i;
#pragma unroll
      for (int ht = 0; ht < 8; ht++)
        Om[ws][r][ht * 16 + n] = accO[ht][i];
      if (n == 0) { Ml[ws][r][0] = mrow[i]; Ml[ws][r][1] = lrow[i]; }
    }
  }
  for (int gg = 1; gg < 4; gg++) {
    __syncthreads();
    if (g == gg) {
#pragma unroll
      for (int i = 0; i < 4; i++) {
        int r = quad * 4 + i;
        float m1 = Ml[ws][r][0], l1 = Ml[ws][r][1];
        float mnew = fmaxf(mrow[i], m1);
        float a0 = __expf(mrow[i] - mnew);   // 0 when this phase had no tiles
        float a1 = __expf(m1 - mnew);
        if (n == 0) { Ml[ws][r][0] = mnew; Ml[ws][r][1] = lrow[i] * a0 + l1 * a1; }
#pragma unroll
        for (int ht = 0; ht < 8; ht++)
          Om[ws][r][ht * 16 + n] = accO[ht][i] * a0 + Om[ws][r][ht * 16 + n] * a1;
      }
    }
  }
  __syncthreads();
  if (g == 0) {
#pragma unroll
    for (int i = 0; i < 4; i++) {
      int r = quad * 4 + i;
      float linv = 1.0f / Ml[ws][r][1];
      size_t base = (size_t)(b * T_DIM + q0 + ws * 16 + r) * H_DIM;
#pragma unroll
      for (int ht = 0; ht < 8; ht++)
        out[base + ht * 16 + n] = Om[ws][r][ht * 16 + n] * linv;
    }
  }
}

// ---------------------------------------------------------------------------
extern "C" void kernel_launch(void* const* d_in, const int* in_sizes, int n_in,
                              void* d_out, int out_size, void* d_ws, size_t ws_size,
                              hipStream_t stream) {
  (void)in_sizes; (void)n_in; (void)out_size; (void)ws_size;
  const float* x  = (const float*)d_in[0];
  const float* Wk = (const float*)d_in[1];
  const float* Wq = (const float*)d_in[2];
  const float* Wv = (const float*)d_in[3];
  float* out = (float*)d_out;

  char* ws = (char*)d_ws;
  short* Wt = (short*)ws;                               // 786,432 B
  short* Kb = (short*)(ws + 786432);                    // 4 MB
  short* Qb = (short*)(ws + 786432 + 4194304);          // 4 MB
  short* Vt = (short*)(ws + 786432 + 8388608);          // [8][128][2048] bf16, 4 MB
  short* xb = (short*)(ws + 786432 + 12582912);         // [B*T][C] bf16, 32 MB

  prep_kernel<<<dim3((NXE + NWE) / 256), dim3(256), 0, stream>>>(x, Wk, Wq, Wv, xb, Wt);
  proj_kernel<<<dim3(256, 3), dim3(256), 0, stream>>>(xb, Wt, Kb, Qb, Vt);
  attn_kernel<<<dim3(64, 8), dim3(512), 0, stream>>>(Qb, Kb, Vt, out);
}

// Round 3
// 215.258 us; speedup vs baseline: 1.0610x; 1.0610x over previous
//
#include <hip/hip_runtime.h>

#define B_DIM 8
#define T_DIM 2048
#define C_DIM 1024
#define H_DIM 128

typedef __attribute__((ext_vector_type(8))) short bf16x8;
typedef __attribute__((ext_vector_type(4))) float f32x4;

__device__ __forceinline__ short f2bf(float f) {
  union { float f; unsigned u; } v; v.f = f;
  unsigned u = v.u;
  unsigned r = (u + 0x7FFFu + ((u >> 16) & 1u)) >> 16;
  return (short)r;
}

__device__ __forceinline__ void gload_lds16(const short* g, short* l) {
  __builtin_amdgcn_global_load_lds(
      (const __attribute__((address_space(1))) void*)g,
      (__attribute__((address_space(3))) void*)l, 16, 0, 0);
}

// ---------------------------------------------------------------------------
// Kernel 1: prep.  (a) x fp32 -> bf16 (xb, [B*T][C]).  (b) weights fp32 ->
// bf16 transposed: Wt[3][H=128][C=1024], 16B coalesced writes.
// ---------------------------------------------------------------------------
#define NXE ((B_DIM * T_DIM * C_DIM) / 8)   // 2097152 x-items (8 elems each)
#define NWE ((3 * C_DIM * H_DIM) / 8)       // 49152 w-items

__global__ __launch_bounds__(256) void prep_kernel(
    const float* __restrict__ x, const float* __restrict__ Wk,
    const float* __restrict__ Wq, const float* __restrict__ Wv,
    short* __restrict__ xb, short* __restrict__ Wt) {
  int gid = blockIdx.x * 256 + threadIdx.x;
  if (gid < NXE) {
    const float* src = x + (size_t)gid * 8;
    float4 f0 = ((const float4*)src)[0];
    float4 f1 = ((const float4*)src)[1];
    __attribute__((aligned(16))) short t[8];
    t[0] = f2bf(f0.x); t[1] = f2bf(f0.y); t[2] = f2bf(f0.z); t[3] = f2bf(f0.w);
    t[4] = f2bf(f1.x); t[5] = f2bf(f1.y); t[6] = f2bf(f1.z); t[7] = f2bf(f1.w);
    ((int4*)xb)[gid] = *(const int4*)t;
  } else {
    int j = gid - NXE;
    if (j >= NWE) return;
    int w = j >> 14;             // /16384 items per weight
    int r = j & 16383;
    int h = r >> 7;              // C/8 = 128 items per h
    int c0 = (r & 127) * 8;
    const float* W = (w == 0) ? Wk : ((w == 1) ? Wq : Wv);
    __attribute__((aligned(16))) short t[8];
#pragma unroll
    for (int i = 0; i < 8; i++) t[i] = f2bf(W[(size_t)(c0 + i) * H_DIM + h]);
    *(int4*)(Wt + (size_t)w * (C_DIM * H_DIM) + h * C_DIM + c0) = *(const int4*)t;
  }
}

// ---------------------------------------------------------------------------
// Kernel 2: projection GEMM — m97-exact structure (874-912 TF proven):
// 128x128 tile, BK=32, 4 waves (2x2 of 64x64), linear LDS + gload_lds x16.
// wi = 0 -> K, 1 -> Q (row-major [t][h]), 2 -> V transposed ([h][t]).
// ---------------------------------------------------------------------------
__global__ __launch_bounds__(256) void proj_kernel(
    const short* __restrict__ xb, const short* __restrict__ Wt,
    short* __restrict__ Kb, short* __restrict__ Qb, short* __restrict__ Vt) {
  const int wi = blockIdx.y;
  const int m0 = blockIdx.x * 128;
  __shared__ short As[128 * 32];
  __shared__ short Bs[128 * 32];
  const int tid  = threadIdx.x;
  const int lane = tid & 63;
  const int wv   = tid >> 6;
  const int n    = lane & 15;
  const int quad = lane >> 4;
  const int mbase = (wv >> 1) * 64;
  const int nbase = (wv & 1) * 64;
  const short* Wp = Wt + (size_t)wi * (C_DIM * H_DIM);

  const int lr = lane >> 2;          // 0..15 row within 1KB chunk
  const int lc = (lane & 3) * 8;     // col offset 0,8,16,24

  f32x4 acc[4][4];
#pragma unroll
  for (int i = 0; i < 4; i++)
#pragma unroll
    for (int j = 0; j < 4; j++) {
      f32x4 z = {0.f, 0.f, 0.f, 0.f};
      acc[i][j] = z;
    }

  for (int k0 = 0; k0 < C_DIM; k0 += 32) {
    __syncthreads();
#pragma unroll
    for (int h = 0; h < 2; h++) {
      int ch = wv * 2 + h;                 // wave-uniform chunk id
      int row = ch * 16 + lr;
      gload_lds16(xb + (size_t)(m0 + row) * C_DIM + k0 + lc, &As[ch * 512]);
      gload_lds16(Wp + (size_t)row * C_DIM + k0 + lc, &Bs[ch * 512]);
    }
    __syncthreads();   // compiler drains vmcnt here (m97 structure)

    bf16x8 aF[4], bF[4];
#pragma unroll
    for (int mt = 0; mt < 4; mt++)
      aF[mt] = *(const bf16x8*)&As[(mbase + mt * 16 + n) * 32 + quad * 8];
#pragma unroll
    for (int nt = 0; nt < 4; nt++)
      bF[nt] = *(const bf16x8*)&Bs[(nbase + nt * 16 + n) * 32 + quad * 8];
#pragma unroll
    for (int mt = 0; mt < 4; mt++)
#pragma unroll
      for (int nt = 0; nt < 4; nt++)
        acc[mt][nt] = __builtin_amdgcn_mfma_f32_16x16x32_bf16(
            aF[mt], bF[nt], acc[mt][nt], 0, 0, 0);
  }

  // epilogue: C/D layout col = lane&15, row = quad*4 + reg
#pragma unroll
  for (int mt = 0; mt < 4; mt++) {
#pragma unroll
    for (int nt = 0; nt < 4; nt++) {
#pragma unroll
      for (int i = 0; i < 4; i++) {
        int row = m0 + mbase + mt * 16 + quad * 4 + i;   // token index
        int col = nbase + nt * 16 + n;                   // h index
        short v = f2bf(acc[mt][nt][i]);
        if (wi == 0) {
          Kb[(size_t)row * H_DIM + col] = v;
        } else if (wi == 1) {
          Qb[(size_t)row * H_DIM + col] = v;
        } else {
          int bb = row >> 11;
          int t = row & (T_DIM - 1);
          Vt[((size_t)bb * H_DIM + col) * T_DIM + t] = v;
        }
      }
    }
  }
}

// ---------------------------------------------------------------------------
// Kernel 3: causal flash attention.  Barrier-free main loop, K/V direct from
// global (L2/L3-resident; FETCH_SIZE r2 = 6MB proves it).  Fix vs r2: operand
// loads REGISTER-BATCHED 8-at-a-time (r2's VGPR=60 serialized all 32 loads).
// Block = 256 thr = 4 waves, ALL on the same 16 Q-rows; wave g handles kv
// tiles t = g, g+4, ...  Grid (128,8) = 1024 blocks = 4 blocks/CU.
// Batch pinned to XCD via id&7 (round-robin dispatch assumption; harmless
// if wrong).  4-way partial merge in LDS at the end.
// ---------------------------------------------------------------------------
__global__ __launch_bounds__(256) void attn_kernel(
    const short* __restrict__ Qb, const short* __restrict__ Kb,
    const short* __restrict__ Vt, float* __restrict__ out) {
  const int id = blockIdx.y * 128 + blockIdx.x;
  const int b  = id & 7;            // batch -> XCD pinning
  const int qt = id >> 3;           // 0..127
  const int q0 = qt * 16;
  const int tid  = threadIdx.x;
  const int lane = tid & 63;
  const int g    = tid >> 6;   // kv phase 0..3
  const int n    = lane & 15;
  const int quad = lane >> 4;

  __shared__ short Ps[4][16][72];   // per-wave P strips (9.2KB)
  __shared__ float Om[16][128];     // merge buffer (8KB)
  __shared__ float Ml[16][2];

  const int ntiles = (qt >> 2) + 1;
  const float scale = 0.08838834764831845f;  // 1/sqrt(128)
  const int row0 = q0 + quad * 4;            // + reg i

  const short* Kb0 = Kb + (size_t)b * T_DIM * H_DIM;
  const short* Vb0 = Vt + (size_t)b * H_DIM * T_DIM;

  // Q A-frags (same for all 4 waves)
  bf16x8 aQ[4];
  {
    const short* qrow = Qb + (size_t)(b * T_DIM + q0 + n) * H_DIM;
#pragma unroll
    for (int kc = 0; kc < 4; kc++)
      aQ[kc] = *(const bf16x8*)(qrow + kc * 32 + quad * 8);
  }

  f32x4 accO[8];
#pragma unroll
  for (int i = 0; i < 8; i++) {
    f32x4 z = {0.f, 0.f, 0.f, 0.f};
    accO[i] = z;
  }
  float mrow[4] = {-1e30f, -1e30f, -1e30f, -1e30f};
  float lrow[4] = {0.f, 0.f, 0.f, 0.f};

  for (int t = g; t < ntiles; t += 4) {
    const int j0 = t * 64;
    f32x4 accS[4];
#pragma unroll
    for (int nt = 0; nt < 4; nt++) {
      f32x4 z = {0.f, 0.f, 0.f, 0.f};
      accS[nt] = z;
    }
    bf16x8 fr[8];
    // ---- K batch 0 (nt 0,1): 8 fragment loads, then 8 MFMAs ----
#pragma unroll
    for (int nt = 0; nt < 2; nt++) {
      const short* kr = Kb0 + (size_t)(j0 + nt * 16 + n) * H_DIM;
#pragma unroll
      for (int kc = 0; kc < 4; kc++)
        fr[nt * 4 + kc] = *(const bf16x8*)(kr + kc * 32 + quad * 8);
    }
    __builtin_amdgcn_sched_barrier(0);
#pragma unroll
    for (int nt = 0; nt < 2; nt++)
#pragma unroll
      for (int kc = 0; kc < 4; kc++)
        accS[nt] = __builtin_amdgcn_mfma_f32_16x16x32_bf16(
            aQ[kc], fr[nt * 4 + kc], accS[nt], 0, 0, 0);
    __builtin_amdgcn_sched_barrier(0);
    // ---- K batch 1 (nt 2,3) ----
#pragma unroll
    for (int nt = 0; nt < 2; nt++) {
      const short* kr = Kb0 + (size_t)(j0 + (nt + 2) * 16 + n) * H_DIM;
#pragma unroll
      for (int kc = 0; kc < 4; kc++)
        fr[nt * 4 + kc] = *(const bf16x8*)(kr + kc * 32 + quad * 8);
    }
    __builtin_amdgcn_sched_barrier(0);
#pragma unroll
    for (int nt = 0; nt < 2; nt++)
#pragma unroll
      for (int kc = 0; kc < 4; kc++)
        accS[nt + 2] = __builtin_amdgcn_mfma_f32_16x16x32_bf16(
            aQ[kc], fr[nt * 4 + kc], accS[nt + 2], 0, 0, 0);
    __builtin_amdgcn_sched_barrier(0);

    // ---- scale + causal mask + row max ----
    float mt4[4] = {-1e30f, -1e30f, -1e30f, -1e30f};
#pragma unroll
    for (int nt = 0; nt < 4; nt++) {
      int col = j0 + nt * 16 + n;
#pragma unroll
      for (int i = 0; i < 4; i++) {
        float s = accS[nt][i] * scale;
        s = (col > row0 + i) ? -1e30f : s;
        accS[nt][i] = s;
        mt4[i] = fmaxf(mt4[i], s);
      }
    }
#pragma unroll
    for (int i = 0; i < 4; i++) {
#pragma unroll
      for (int off = 1; off < 16; off <<= 1)
        mt4[i] = fmaxf(mt4[i], __shfl_xor(mt4[i], off, 64));
    }

    // ---- V batch 0 prefetch (ht 0..3): latency hidden under softmax ----
    bf16x8 frv[8];
#pragma unroll
    for (int ht = 0; ht < 4; ht++) {
      const short* vr = Vb0 + (size_t)(ht * 16 + n) * T_DIM + j0;
#pragma unroll
      for (int kc = 0; kc < 2; kc++)
        frv[ht * 2 + kc] = *(const bf16x8*)(vr + kc * 32 + quad * 8);
    }
    __builtin_amdgcn_sched_barrier(0);

    // ---- softmax: exp, P write, row sum, rescale ----
    float alpha[4], rsum[4];
#pragma unroll
    for (int i = 0; i < 4; i++) {
      float mnew = fmaxf(mrow[i], mt4[i]);
      alpha[i] = __expf(mrow[i] - mnew);
      mrow[i] = mnew;
      rsum[i] = 0.f;
    }
#pragma unroll
    for (int nt = 0; nt < 4; nt++)
#pragma unroll
      for (int i = 0; i < 4; i++) {
        float p = __expf(accS[nt][i] - mrow[i]);
        rsum[i] += p;
        Ps[g][quad * 4 + i][nt * 16 + n] = f2bf(p);
      }
#pragma unroll
    for (int i = 0; i < 4; i++) {
#pragma unroll
      for (int off = 1; off < 16; off <<= 1)
        rsum[i] += __shfl_xor(rsum[i], off, 64);
      lrow[i] = lrow[i] * alpha[i] + rsum[i];
    }
#pragma unroll
    for (int ht = 0; ht < 8; ht++)
#pragma unroll
      for (int i = 0; i < 4; i++)
        accO[ht][i] *= alpha[i];

    // P strip written+read by the SAME wave: lgkmcnt wait suffices (rule 18)
    asm volatile("s_waitcnt lgkmcnt(0)" ::: "memory");
    __builtin_amdgcn_sched_barrier(0);

    bf16x8 aP[2];
#pragma unroll
    for (int kc = 0; kc < 2; kc++)
      aP[kc] = *(const bf16x8*)&Ps[g][n][kc * 32 + quad * 8];

    // ---- PV batch 0 (ht 0..3) ----
#pragma unroll
    for (int ht = 0; ht < 4; ht++)
#pragma unroll
      for (int kc = 0; kc < 2; kc++)
        accO[ht] = __builtin_amdgcn_mfma_f32_16x16x32_bf16(
            aP[kc], frv[ht * 2 + kc], accO[ht], 0, 0, 0);
    __builtin_amdgcn_sched_barrier(0);
    // ---- V batch 1 (ht 4..7) ----
#pragma unroll
    for (int ht = 0; ht < 4; ht++) {
      const short* vr = Vb0 + (size_t)((ht + 4) * 16 + n) * T_DIM + j0;
#pragma unroll
      for (int kc = 0; kc < 2; kc++)
        frv[ht * 2 + kc] = *(const bf16x8*)(vr + kc * 32 + quad * 8);
    }
    __builtin_amdgcn_sched_barrier(0);
#pragma unroll
    for (int ht = 0; ht < 4; ht++)
#pragma unroll
      for (int kc = 0; kc < 2; kc++)
        accO[ht + 4] = __builtin_amdgcn_mfma_f32_16x16x32_bf16(
            aP[kc], frv[ht * 2 + kc], accO[ht + 4], 0, 0, 0);
  }

  // ---- merge the 4 kv-phase partials (only barriers in the kernel) ----
  __syncthreads();
  if (g == 0) {
#pragma unroll
    for (int i = 0; i < 4; i++) {
      int r = quad * 4 + i;
#pragma unroll
      for (int ht = 0; ht < 8; ht++)
        Om[r][ht * 16 + n] = accO[ht][i];
      if (n == 0) { Ml[r][0] = mrow[i]; Ml[r][1] = lrow[i]; }
    }
  }
#pragma unroll
  for (int gg = 1; gg < 4; gg++) {
    __syncthreads();
    if (g == gg) {
#pragma unroll
      for (int i = 0; i < 4; i++) {
        int r = quad * 4 + i;
        float m1 = Ml[r][0], l1 = Ml[r][1];
        float mnew = fmaxf(mrow[i], m1);
        float a0 = __expf(mrow[i] - mnew);   // 0 when this phase had no tiles
        float a1 = __expf(m1 - mnew);
        float lnew = lrow[i] * a0 + l1 * a1;
        if (gg < 3) {
          if (n == 0) { Ml[r][0] = mnew; Ml[r][1] = lnew; }
#pragma unroll
          for (int ht = 0; ht < 8; ht++)
            Om[r][ht * 16 + n] = accO[ht][i] * a0 + Om[r][ht * 16 + n] * a1;
        } else {
          float linv = 1.0f / lnew;
          size_t base = (size_t)(b * T_DIM + q0 + r) * H_DIM;
#pragma unroll
          for (int ht = 0; ht < 8; ht++)
            out[base + ht * 16 + n] =
                (accO[ht][i] * a0 + Om[r][ht * 16 + n] * a1) * linv;
        }
      }
    }
  }
}

// ---------------------------------------------------------------------------
extern "C" void kernel_launch(void* const* d_in, const int* in_sizes, int n_in,
                              void* d_out, int out_size, void* d_ws, size_t ws_size,
                              hipStream_t stream) {
  (void)in_sizes; (void)n_in; (void)out_size; (void)ws_size;
  const float* x  = (const float*)d_in[0];
  const float* Wk = (const float*)d_in[1];
  const float* Wq = (const float*)d_in[2];
  const float* Wv = (const float*)d_in[3];
  float* out = (float*)d_out;

  char* ws = (char*)d_ws;
  short* Wt = (short*)ws;                               // 786,432 B
  short* Kb = (short*)(ws + 786432);                    // 4 MB
  short* Qb = (short*)(ws + 786432 + 4194304);          // 4 MB
  short* Vt = (short*)(ws + 786432 + 8388608);          // [8][128][2048] bf16, 4 MB
  short* xb = (short*)(ws + 786432 + 12582912);         // [B*T][C] bf16, 32 MB

  prep_kernel<<<dim3((NXE + NWE) / 256), dim3(256), 0, stream>>>(x, Wk, Wq, Wv, xb, Wt);
  proj_kernel<<<dim3(128, 3), dim3(256), 0, stream>>>(xb, Wt, Kb, Qb, Vt);
  attn_kernel<<<dim3(128, 8), dim3(256), 0, stream>>>(Qb, Kb, Vt, out);
}

// Round 4
// 178.482 us; speedup vs baseline: 1.2796x; 1.2061x over previous
//
#include <hip/hip_runtime.h>

#define B_DIM 8
#define T_DIM 2048
#define C_DIM 1024
#define H_DIM 128

typedef __attribute__((ext_vector_type(8))) short bf16x8;
typedef __attribute__((ext_vector_type(4))) float f32x4;

__device__ __forceinline__ short f2bf(float f) {
  union { float f; unsigned u; } v; v.f = f;
  unsigned u = v.u;
  unsigned r = (u + 0x7FFFu + ((u >> 16) & 1u)) >> 16;
  return (short)r;
}

__device__ __forceinline__ void gload_lds16(const short* g, short* l) {
  __builtin_amdgcn_global_load_lds(
      (const __attribute__((address_space(1))) void*)g,
      (__attribute__((address_space(3))) void*)l, 16, 0, 0);
}

// DPP rotate-reduce over the 16-lane row (n = lane&15), VALU-speed.
__device__ __forceinline__ float rowmax16(float x) {
  union { float f; int i; } a, t;
  a.f = x;
  t.i = __builtin_amdgcn_update_dpp(a.i, a.i, 0x128, 0xf, 0xf, false);  // ror:8
  a.f = fmaxf(a.f, t.f);
  t.i = __builtin_amdgcn_update_dpp(a.i, a.i, 0x124, 0xf, 0xf, false);  // ror:4
  a.f = fmaxf(a.f, t.f);
  t.i = __builtin_amdgcn_update_dpp(a.i, a.i, 0x122, 0xf, 0xf, false);  // ror:2
  a.f = fmaxf(a.f, t.f);
  t.i = __builtin_amdgcn_update_dpp(a.i, a.i, 0x121, 0xf, 0xf, false);  // ror:1
  a.f = fmaxf(a.f, t.f);
  return a.f;
}
__device__ __forceinline__ float rowsum16(float x) {
  union { float f; int i; } a, t;
  a.f = x;
  t.i = __builtin_amdgcn_update_dpp(a.i, a.i, 0x128, 0xf, 0xf, false);
  a.f += t.f;
  t.i = __builtin_amdgcn_update_dpp(a.i, a.i, 0x124, 0xf, 0xf, false);
  a.f += t.f;
  t.i = __builtin_amdgcn_update_dpp(a.i, a.i, 0x122, 0xf, 0xf, false);
  a.f += t.f;
  t.i = __builtin_amdgcn_update_dpp(a.i, a.i, 0x121, 0xf, 0xf, false);
  a.f += t.f;
  return a.f;
}

// ---------------------------------------------------------------------------
// Kernel 1: prep.  (a) x fp32 -> bf16 (xb, [B*T][C]).  (b) weights fp32 ->
// bf16 transposed: Wt[3][H=128][C=1024], 16B coalesced writes.
// ---------------------------------------------------------------------------
#define NXE ((B_DIM * T_DIM * C_DIM) / 8)   // 2097152 x-items (8 elems each)
#define NWE ((3 * C_DIM * H_DIM) / 8)       // 49152 w-items

__global__ __launch_bounds__(256) void prep_kernel(
    const float* __restrict__ x, const float* __restrict__ Wk,
    const float* __restrict__ Wq, const float* __restrict__ Wv,
    short* __restrict__ xb, short* __restrict__ Wt) {
  int gid = blockIdx.x * 256 + threadIdx.x;
  if (gid < NXE) {
    const float* src = x + (size_t)gid * 8;
    float4 f0 = ((const float4*)src)[0];
    float4 f1 = ((const float4*)src)[1];
    __attribute__((aligned(16))) short t[8];
    t[0] = f2bf(f0.x); t[1] = f2bf(f0.y); t[2] = f2bf(f0.z); t[3] = f2bf(f0.w);
    t[4] = f2bf(f1.x); t[5] = f2bf(f1.y); t[6] = f2bf(f1.z); t[7] = f2bf(f1.w);
    ((int4*)xb)[gid] = *(const int4*)t;
  } else {
    int j = gid - NXE;
    if (j >= NWE) return;
    int w = j >> 14;             // /16384 items per weight
    int r = j & 16383;
    int h = r >> 7;              // C/8 = 128 items per h
    int c0 = (r & 127) * 8;
    const float* W = (w == 0) ? Wk : ((w == 1) ? Wq : Wv);
    __attribute__((aligned(16))) short t[8];
#pragma unroll
    for (int i = 0; i < 8; i++) t[i] = f2bf(W[(size_t)(c0 + i) * H_DIM + h]);
    *(int4*)(Wt + (size_t)w * (C_DIM * H_DIM) + h * C_DIM + c0) = *(const int4*)t;
  }
}

// ---------------------------------------------------------------------------
// Kernel 2: projection GEMM — m97 structure (128x128, BK=32, gload_lds x16).
// Epilogue writes K and V in MFMA-FRAGMENT-PACKED layout so attn's operand
// loads are single contiguous 1KB segments (r3's were 16-segment gathers):
//   Kp[b][t64][nt(4)][kc(4)][lane(64)][8]   lane = quad*16 + n
//   Vp[b][t64][ht(8)][kc(2)][lane(64)][8]
// Q stays row-major [b*T+t][h].
// ---------------------------------------------------------------------------
__global__ __launch_bounds__(256) void proj_kernel(
    const short* __restrict__ xb, const short* __restrict__ Wt,
    short* __restrict__ Kp, short* __restrict__ Qb, short* __restrict__ Vp) {
  const int wi = blockIdx.y;
  const int m0 = blockIdx.x * 128;
  __shared__ short As[128 * 32];
  __shared__ short Bs[128 * 32];
  const int tid  = threadIdx.x;
  const int lane = tid & 63;
  const int wv   = tid >> 6;
  const int n    = lane & 15;
  const int quad = lane >> 4;
  const int mbase = (wv >> 1) * 64;
  const int nbase = (wv & 1) * 64;
  const short* Wp = Wt + (size_t)wi * (C_DIM * H_DIM);

  const int lr = lane >> 2;          // 0..15 row within 1KB chunk
  const int lc = (lane & 3) * 8;     // col offset 0,8,16,24

  f32x4 acc[4][4];
#pragma unroll
  for (int i = 0; i < 4; i++)
#pragma unroll
    for (int j = 0; j < 4; j++) {
      f32x4 z = {0.f, 0.f, 0.f, 0.f};
      acc[i][j] = z;
    }

  for (int k0 = 0; k0 < C_DIM; k0 += 32) {
    __syncthreads();
#pragma unroll
    for (int h = 0; h < 2; h++) {
      int ch = wv * 2 + h;                 // wave-uniform chunk id
      int row = ch * 16 + lr;
      gload_lds16(xb + (size_t)(m0 + row) * C_DIM + k0 + lc, &As[ch * 512]);
      gload_lds16(Wp + (size_t)row * C_DIM + k0 + lc, &Bs[ch * 512]);
    }
    __syncthreads();   // compiler drains vmcnt here (m97 structure)

    bf16x8 aF[4], bF[4];
#pragma unroll
    for (int mt = 0; mt < 4; mt++)
      aF[mt] = *(const bf16x8*)&As[(mbase + mt * 16 + n) * 32 + quad * 8];
#pragma unroll
    for (int nt = 0; nt < 4; nt++)
      bF[nt] = *(const bf16x8*)&Bs[(nbase + nt * 16 + n) * 32 + quad * 8];
#pragma unroll
    for (int mt = 0; mt < 4; mt++)
#pragma unroll
      for (int nt = 0; nt < 4; nt++)
        acc[mt][nt] = __builtin_amdgcn_mfma_f32_16x16x32_bf16(
            aF[mt], bF[nt], acc[mt][nt], 0, 0, 0);
  }

  // epilogue: C/D layout col = lane&15, row = quad*4 + reg
#pragma unroll
  for (int mt = 0; mt < 4; mt++) {
#pragma unroll
    for (int nt = 0; nt < 4; nt++) {
#pragma unroll
      for (int i = 0; i < 4; i++) {
        int row = m0 + mbase + mt * 16 + quad * 4 + i;   // global token index
        int col = nbase + nt * 16 + n;                   // h index
        short v = f2bf(acc[mt][nt][i]);
        int bb = row >> 11;
        int t  = row & (T_DIM - 1);
        int tt = t >> 6;
        if (wi == 0) {
          // K fragment pack
          int rr = t & 63;
          int knt = rr >> 4, kn = rr & 15;
          int kc = col >> 5, kq = (col >> 3) & 3, kj = col & 7;
          Kp[(((size_t)(bb * 32 + tt) * 16 + knt * 4 + kc) * 512) +
             (kq * 16 + kn) * 8 + kj] = v;
        } else if (wi == 1) {
          Qb[(size_t)row * H_DIM + col] = v;
        } else {
          // V fragment pack
          int vkc = (t >> 5) & 1, vq = (t >> 3) & 3, vj = t & 7;
          int ht = col >> 4, vn = col & 15;
          Vp[(((size_t)(bb * 32 + tt) * 16 + ht * 2 + vkc) * 512) +
             (vq * 16 + vn) * 8 + vj] = v;
        }
      }
    }
  }
}

// ---------------------------------------------------------------------------
// Kernel 3: causal flash attention.  Barrier-free main loop; K/V read from
// the fragment-packed buffers: each operand load = base + lane*16B, ONE
// contiguous 1KB segment (r3's 16-segment gathers were the serializer).
// Softmax reductions via DPP row_ror (r3's 32 chained ds_bpermutes ~2Kcy).
// Block = 256 thr = 4 waves on the same 16 Q-rows; wave g does kv tiles
// t = g, g+4, ...; grid (128,8) = 1024 blocks = 4 blocks/CU; 4-way merge.
// ---------------------------------------------------------------------------
__global__ __launch_bounds__(256, 4) void attn_kernel(
    const short* __restrict__ Qb, const short* __restrict__ Kp,
    const short* __restrict__ Vp, float* __restrict__ out) {
  const int id = blockIdx.y * 128 + blockIdx.x;
  const int b  = id & 7;            // batch -> XCD pinning
  const int qt = id >> 3;           // 0..127
  const int q0 = qt * 16;
  const int tid  = threadIdx.x;
  const int lane = tid & 63;
  const int g    = tid >> 6;   // kv phase 0..3
  const int n    = lane & 15;
  const int quad = lane >> 4;

  __shared__ short Ps[4][16][72];   // per-wave P strips (9.2KB)
  __shared__ float Om[16][128];     // merge buffer (8KB)
  __shared__ float Ml[16][2];

  const int ntiles = (qt >> 2) + 1;
  const float scale = 0.08838834764831845f;  // 1/sqrt(128)
  const int row0 = q0 + quad * 4;            // + reg i

  const short* Kbase = Kp + (size_t)b * 32 * 16 * 512;
  const short* Vbase = Vp + (size_t)b * 32 * 16 * 512;

  // Q A-frags (same for all 4 waves)
  bf16x8 aQ[4];
  {
    const short* qrow = Qb + (size_t)(b * T_DIM + q0 + n) * H_DIM;
#pragma unroll
    for (int kc = 0; kc < 4; kc++)
      aQ[kc] = *(const bf16x8*)(qrow + kc * 32 + quad * 8);
  }

  f32x4 accO[8];
#pragma unroll
  for (int i = 0; i < 8; i++) {
    f32x4 z = {0.f, 0.f, 0.f, 0.f};
    accO[i] = z;
  }
  float mrow[4] = {-1e30f, -1e30f, -1e30f, -1e30f};
  float lrow[4] = {0.f, 0.f, 0.f, 0.f};

  for (int t = g; t < ntiles; t += 4) {
    const int j0 = t * 64;
    const short* Kt = Kbase + (size_t)t * 16 * 512 + lane * 8;
    const short* Vt = Vbase + (size_t)t * 16 * 512 + lane * 8;
    f32x4 accS[4];
#pragma unroll
    for (int nt = 0; nt < 4; nt++) {
      f32x4 z = {0.f, 0.f, 0.f, 0.f};
      accS[nt] = z;
    }
    bf16x8 fr[8];
    // ---- K batch 0 (nt 0,1): 8 coalesced 1KB loads, then 8 MFMAs ----
#pragma unroll
    for (int nt = 0; nt < 2; nt++)
#pragma unroll
      for (int kc = 0; kc < 4; kc++)
        fr[nt * 4 + kc] = *(const bf16x8*)(Kt + (nt * 4 + kc) * 512);
    __builtin_amdgcn_sched_barrier(0);
#pragma unroll
    for (int nt = 0; nt < 2; nt++)
#pragma unroll
      for (int kc = 0; kc < 4; kc++)
        accS[nt] = __builtin_amdgcn_mfma_f32_16x16x32_bf16(
            aQ[kc], fr[nt * 4 + kc], accS[nt], 0, 0, 0);
    __builtin_amdgcn_sched_barrier(0);
    // ---- K batch 1 (nt 2,3) ----
#pragma unroll
    for (int nt = 0; nt < 2; nt++)
#pragma unroll
      for (int kc = 0; kc < 4; kc++)
        fr[nt * 4 + kc] = *(const bf16x8*)(Kt + ((nt + 2) * 4 + kc) * 512);
    __builtin_amdgcn_sched_barrier(0);
#pragma unroll
    for (int nt = 0; nt < 2; nt++)
#pragma unroll
      for (int kc = 0; kc < 4; kc++)
        accS[nt + 2] = __builtin_amdgcn_mfma_f32_16x16x32_bf16(
            aQ[kc], fr[nt * 4 + kc], accS[nt + 2], 0, 0, 0);
    __builtin_amdgcn_sched_barrier(0);

    // ---- scale + causal mask + row max (DPP) ----
    float mt4[4] = {-1e30f, -1e30f, -1e30f, -1e30f};
#pragma unroll
    for (int nt = 0; nt < 4; nt++) {
      int col = j0 + nt * 16 + n;
#pragma unroll
      for (int i = 0; i < 4; i++) {
        float s = accS[nt][i] * scale;
        s = (col > row0 + i) ? -1e30f : s;
        accS[nt][i] = s;
        mt4[i] = fmaxf(mt4[i], s);
      }
    }
#pragma unroll
    for (int i = 0; i < 4; i++) mt4[i] = rowmax16(mt4[i]);

    // ---- V batch 0 prefetch (ht 0..3): latency hidden under softmax ----
    bf16x8 frv[8];
#pragma unroll
    for (int ht = 0; ht < 4; ht++)
#pragma unroll
      for (int kc = 0; kc < 2; kc++)
        frv[ht * 2 + kc] = *(const bf16x8*)(Vt + (ht * 2 + kc) * 512);
    __builtin_amdgcn_sched_barrier(0);

    // ---- softmax: exp, P write, row sum (DPP), rescale ----
    float alpha[4], rsum[4];
#pragma unroll
    for (int i = 0; i < 4; i++) {
      float mnew = fmaxf(mrow[i], mt4[i]);
      alpha[i] = __expf(mrow[i] - mnew);
      mrow[i] = mnew;
      rsum[i] = 0.f;
    }
#pragma unroll
    for (int nt = 0; nt < 4; nt++)
#pragma unroll
      for (int i = 0; i < 4; i++) {
        float p = __expf(accS[nt][i] - mrow[i]);
        rsum[i] += p;
        Ps[g][quad * 4 + i][nt * 16 + n] = f2bf(p);
      }
#pragma unroll
    for (int i = 0; i < 4; i++) {
      rsum[i] = rowsum16(rsum[i]);
      lrow[i] = lrow[i] * alpha[i] + rsum[i];
    }
#pragma unroll
    for (int ht = 0; ht < 8; ht++)
#pragma unroll
      for (int i = 0; i < 4; i++)
        accO[ht][i] *= alpha[i];

    // P strip written+read by the SAME wave: lgkmcnt wait suffices (rule 18)
    asm volatile("s_waitcnt lgkmcnt(0)" ::: "memory");
    __builtin_amdgcn_sched_barrier(0);

    bf16x8 aP[2];
#pragma unroll
    for (int kc = 0; kc < 2; kc++)
      aP[kc] = *(const bf16x8*)&Ps[g][n][kc * 32 + quad * 8];

    // ---- PV batch 0 (ht 0..3) ----
#pragma unroll
    for (int ht = 0; ht < 4; ht++)
#pragma unroll
      for (int kc = 0; kc < 2; kc++)
        accO[ht] = __builtin_amdgcn_mfma_f32_16x16x32_bf16(
            aP[kc], frv[ht * 2 + kc], accO[ht], 0, 0, 0);
    __builtin_amdgcn_sched_barrier(0);
    // ---- V batch 1 (ht 4..7) ----
#pragma unroll
    for (int ht = 0; ht < 4; ht++)
#pragma unroll
      for (int kc = 0; kc < 2; kc++)
        frv[ht * 2 + kc] = *(const bf16x8*)(Vt + ((ht + 4) * 2 + kc) * 512);
    __builtin_amdgcn_sched_barrier(0);
#pragma unroll
    for (int ht = 0; ht < 4; ht++)
#pragma unroll
      for (int kc = 0; kc < 2; kc++)
        accO[ht + 4] = __builtin_amdgcn_mfma_f32_16x16x32_bf16(
            aP[kc], frv[ht * 2 + kc], accO[ht + 4], 0, 0, 0);
  }

  // ---- merge the 4 kv-phase partials (only barriers in the kernel) ----
  __syncthreads();
  if (g == 0) {
#pragma unroll
    for (int i = 0; i < 4; i++) {
      int r = quad * 4 + i;
#pragma unroll
      for (int ht = 0; ht < 8; ht++)
        Om[r][ht * 16 + n] = accO[ht][i];
      if (n == 0) { Ml[r][0] = mrow[i]; Ml[r][1] = lrow[i]; }
    }
  }
#pragma unroll
  for (int gg = 1; gg < 4; gg++) {
    __syncthreads();
    if (g == gg) {
#pragma unroll
      for (int i = 0; i < 4; i++) {
        int r = quad * 4 + i;
        float m1 = Ml[r][0], l1 = Ml[r][1];
        float mnew = fmaxf(mrow[i], m1);
        float a0 = __expf(mrow[i] - mnew);   // 0 when this phase had no tiles
        float a1 = __expf(m1 - mnew);
        float lnew = lrow[i] * a0 + l1 * a1;
        if (gg < 3) {
          if (n == 0) { Ml[r][0] = mnew; Ml[r][1] = lnew; }
#pragma unroll
          for (int ht = 0; ht < 8; ht++)
            Om[r][ht * 16 + n] = accO[ht][i] * a0 + Om[r][ht * 16 + n] * a1;
        } else {
          float linv = 1.0f / lnew;
          size_t base = (size_t)(b * T_DIM + q0 + r) * H_DIM;
#pragma unroll
          for (int ht = 0; ht < 8; ht++)
            out[base + ht * 16 + n] =
                (accO[ht][i] * a0 + Om[r][ht * 16 + n] * a1) * linv;
        }
      }
    }
  }
}

// ---------------------------------------------------------------------------
extern "C" void kernel_launch(void* const* d_in, const int* in_sizes, int n_in,
                              void* d_out, int out_size, void* d_ws, size_t ws_size,
                              hipStream_t stream) {
  (void)in_sizes; (void)n_in; (void)out_size; (void)ws_size;
  const float* x  = (const float*)d_in[0];
  const float* Wk = (const float*)d_in[1];
  const float* Wq = (const float*)d_in[2];
  const float* Wv = (const float*)d_in[3];
  float* out = (float*)d_out;

  char* ws = (char*)d_ws;
  short* Wt = (short*)ws;                               // 786,432 B
  short* Kp = (short*)(ws + 786432);                    // 4 MB (fragment-packed)
  short* Qb = (short*)(ws + 786432 + 4194304);          // 4 MB
  short* Vp = (short*)(ws + 786432 + 8388608);          // 4 MB (fragment-packed)
  short* xb = (short*)(ws + 786432 + 12582912);         // [B*T][C] bf16, 32 MB

  prep_kernel<<<dim3((NXE + NWE) / 256), dim3(256), 0, stream>>>(x, Wk, Wq, Wv, xb, Wt);
  proj_kernel<<<dim3(128, 3), dim3(256), 0, stream>>>(xb, Wt, Kp, Qb, Vp);
  attn_kernel<<<dim3(128, 8), dim3(256), 0, stream>>>(Qb, Kp, Vp, out);
}